// Round 17
// baseline (1918.652 us; speedup 1.0000x reference)
//
#include <hip/hip_runtime.h>
#include <hip/hip_bf16.h>
#include <hip/hip_fp16.h>
#include <math.h>

#define UNITS 64
#define DEPTH_EMB 12
#define DEPTH_PAR 5
#define GN_EPS 1e-5f
#define NFILLB 256          // blocks in bucketed fill
#define MAXNB 512           // max buckets (N <= 131072)

// ---------------- CSR build ----------------

__global__ void k_deg(const int* __restrict__ dst, int* __restrict__ cnt, int E) {
    int e = blockIdx.x * blockDim.x + threadIdx.x;
    if (e < E) atomicAdd(&cnt[dst[e]], 1);
}

__global__ void k_dinv(const int* __restrict__ cnt, float* __restrict__ dinv, int n) {
    int i = blockIdx.x * blockDim.x + threadIdx.x;
    if (i < n) dinv[i] = rsqrtf(1.0f + (float)cnt[i]);
}

__global__ void k_chunksum(const int* __restrict__ cnt, int* __restrict__ csum, int n) {
    __shared__ int sd[256];
    int base = blockIdx.x * 1024;
    int s = 0;
    for (int i = threadIdx.x; i < 1024; i += 256) {
        int idx = base + i;
        if (idx < n) s += cnt[idx];
    }
    sd[threadIdx.x] = s;
    __syncthreads();
    for (int off = 128; off > 0; off >>= 1) {
        if (threadIdx.x < off) sd[threadIdx.x] += sd[threadIdx.x + off];
        __syncthreads();
    }
    if (threadIdx.x == 0) csum[blockIdx.x] = sd[0];
}

__global__ void k_scansum(const int* __restrict__ csum, int* __restrict__ coff,
                          int* __restrict__ rowptr, int nchunks) {
    __shared__ int sd[256];
    int tid = threadIdx.x;
    int v = (tid < nchunks) ? csum[tid] : 0;
    sd[tid] = v;
    __syncthreads();
    for (int off = 1; off < 256; off <<= 1) {
        int t = (tid >= off) ? sd[tid - off] : 0;
        __syncthreads();
        sd[tid] += t;
        __syncthreads();
    }
    if (tid < nchunks) coff[tid] = sd[tid] - v;
    if (tid == 0) rowptr[0] = 0;
}

__global__ void k_scanfinal(const int* __restrict__ cnt, const int* __restrict__ coff,
                            int* __restrict__ rowptr, int n) {
    __shared__ int sd[1024];
    int base = blockIdx.x * 1024;
    int tid = threadIdx.x;
    int idx = base + tid;
    int v = (idx < n) ? cnt[idx] : 0;
    sd[tid] = v;
    __syncthreads();
    for (int off = 1; off < 1024; off <<= 1) {
        int t = (tid >= off) ? sd[tid - off] : 0;
        __syncthreads();
        sd[tid] += t;
        __syncthreads();
    }
    if (idx < n) rowptr[idx + 1] = coff[blockIdx.x] + sd[tid];
}

// ---------------- bucketed fill ----------------

__global__ void k_bcount(const int* __restrict__ dst, int* __restrict__ table,
                         int E, int nb, int epb) {
    __shared__ int hist[MAXNB];
    int tid = threadIdx.x;
    for (int i = tid; i < nb; i += 256) hist[i] = 0;
    __syncthreads();
    int e0 = blockIdx.x * epb;
    int e1 = min(e0 + epb, E);
    for (int e = e0 + tid; e < e1; e += 256) atomicAdd(&hist[dst[e] >> 8], 1);
    __syncthreads();
    for (int i = tid; i < nb; i += 256) table[i * NFILLB + blockIdx.x] = hist[i];
}

__global__ void k_bscan(int* __restrict__ table, int* __restrict__ btot) {
    __shared__ int sd[NFILLB];
    int b = blockIdx.x;
    int tid = threadIdx.x;
    int v = table[b * NFILLB + tid];
    sd[tid] = v;
    __syncthreads();
    for (int off = 1; off < NFILLB; off <<= 1) {
        int t = (tid >= off) ? sd[tid - off] : 0;
        __syncthreads();
        sd[tid] += t;
        __syncthreads();
    }
    table[b * NFILLB + tid] = sd[tid] - v;
    if (tid == NFILLB - 1) btot[b] = sd[NFILLB - 1];
}

__global__ void k_boffscan(const int* __restrict__ btot, int* __restrict__ boff, int nb) {
    __shared__ int sd[MAXNB];
    int tid = threadIdx.x;
    int v = (tid < nb) ? btot[tid] : 0;
    sd[tid] = v;
    __syncthreads();
    for (int off = 1; off < MAXNB; off <<= 1) {
        int t = (tid >= off) ? sd[tid - off] : 0;
        __syncthreads();
        sd[tid] += t;
        __syncthreads();
    }
    if (tid < nb) boff[tid] = sd[tid] - v;
}

__global__ void k_bscatter(const int* __restrict__ src, const int* __restrict__ dst,
                           const int* __restrict__ table, const int* __restrict__ boff,
                           unsigned long long* __restrict__ pairs, int E, int nb, int epb) {
    __shared__ int hist[MAXNB];
    int tid = threadIdx.x;
    for (int i = tid; i < nb; i += 256) hist[i] = 0;
    __syncthreads();
    int e0 = blockIdx.x * epb;
    int e1 = min(e0 + epb, E);
    for (int e = e0 + tid; e < e1; e += 256) {
        int d = dst[e];
        int b = d >> 8;
        int local = atomicAdd(&hist[b], 1);
        int p = boff[b] + table[b * NFILLB + blockIdx.x] + local;
        pairs[p] = ((unsigned long long)(unsigned)d << 32) | (unsigned)src[e];
    }
}

__global__ void k_pfill(const unsigned long long* __restrict__ pairs,
                        const int* __restrict__ rowptr, int* __restrict__ fillc,
                        int* __restrict__ srcs, int E) {
    int stride = gridDim.x * blockDim.x;
    for (int idx = blockIdx.x * blockDim.x + threadIdx.x; idx < E; idx += stride) {
        unsigned long long pr = pairs[idx];
        int s = (int)(pr & 0xffffffffu);
        int d = (int)(pr >> 32);
        int p = rowptr[d] + atomicAdd(&fillc[d], 1);
        srcs[p] = s;
    }
}

// ---------------- layer 0: h2 = f16(dinv * (x @ w0)), row-major [N][64] ----------------

__global__ void k_l0(const float* __restrict__ x, const float* __restrict__ w0,
                     const float* __restrict__ dinv, __half* __restrict__ h2, int n) {
    int gid = blockIdx.x * blockDim.x + threadIdx.x;
    if (gid >= n * UNITS) return;
    int node = gid >> 6, c = gid & 63;
    h2[gid] = __float2half(x[node] * w0[c] * dinv[node]);
}

// ---------------- gather: h[d] = dinv[d]*(sum srcs rows + own row) + b ----------------

template <int DO_STATS>
__global__ void k_gather(const __half* __restrict__ h2, float* __restrict__ h,
                         const int* __restrict__ rowptr, const int* __restrict__ srcs,
                         const float* __restrict__ dinv, const float* __restrict__ b,
                         float* __restrict__ stats, int n) {
    int lane = threadIdx.x & 63;
    int wib = threadIdx.x >> 6;
    int wpb = blockDim.x >> 6;
    int gwave = blockIdx.x * wpb + wib;
    int nwaves = gridDim.x * wpb;
    float bj = b[lane];
    float s1 = 0.0f, s2 = 0.0f;

    for (int nd = gwave; nd < n; nd += nwaves) {
        int node = __builtin_amdgcn_readfirstlane(nd);
        int beg = rowptr[node], end = rowptr[node + 1];
        float di = dinv[node];
        float acc0 = __half2float(h2[(size_t)node * UNITS + lane]);   // self row
        float acc1 = 0.0f, acc2 = 0.0f, acc3 = 0.0f;
        int j = beg;
        for (; j + 8 <= end; j += 8) {
            int i0 = srcs[j + 0], i1 = srcs[j + 1], i2 = srcs[j + 2], i3 = srcs[j + 3];
            int i4 = srcs[j + 4], i5 = srcs[j + 5], i6 = srcs[j + 6], i7 = srcs[j + 7];
            float v0 = __half2float(h2[(size_t)i0 * UNITS + lane]);
            float v1 = __half2float(h2[(size_t)i1 * UNITS + lane]);
            float v2 = __half2float(h2[(size_t)i2 * UNITS + lane]);
            float v3 = __half2float(h2[(size_t)i3 * UNITS + lane]);
            float v4 = __half2float(h2[(size_t)i4 * UNITS + lane]);
            float v5 = __half2float(h2[(size_t)i5 * UNITS + lane]);
            float v6 = __half2float(h2[(size_t)i6 * UNITS + lane]);
            float v7 = __half2float(h2[(size_t)i7 * UNITS + lane]);
            acc0 += v0; acc1 += v1; acc2 += v2; acc3 += v3;
            acc0 += v4; acc1 += v5; acc2 += v6; acc3 += v7;
        }
        for (; j + 4 <= end; j += 4) {
            int i0 = srcs[j + 0], i1 = srcs[j + 1], i2 = srcs[j + 2], i3 = srcs[j + 3];
            float v0 = __half2float(h2[(size_t)i0 * UNITS + lane]);
            float v1 = __half2float(h2[(size_t)i1 * UNITS + lane]);
            float v2 = __half2float(h2[(size_t)i2 * UNITS + lane]);
            float v3 = __half2float(h2[(size_t)i3 * UNITS + lane]);
            acc0 += v0; acc1 += v1; acc2 += v2; acc3 += v3;
        }
        for (; j < end; ++j) acc0 += __half2float(h2[(size_t)srcs[j] * UNITS + lane]);
        float acc = (acc0 + acc1) + (acc2 + acc3);
        float hv = fmaf(acc, di, bj);
        h[(size_t)node * UNITS + lane] = hv;
        if (DO_STATS) {
            s1 += hv;
            s2 = fmaf(hv, hv, s2);
        }
    }

    if (DO_STATS) {
        __shared__ float sd[2][4][UNITS];
        sd[0][wib][lane] = s1;
        sd[1][wib][lane] = s2;
        __syncthreads();
        if (threadIdx.x < UNITS) {
            float a1 = 0.0f, a2 = 0.0f;
            for (int r = 0; r < wpb; ++r) {
                a1 += sd[0][r][lane];
                a2 += sd[1][r][lane];
            }
            atomicAdd(&stats[lane], a1);
            atomicAdd(&stats[UNITS + lane], a2);
        }
    }
}

// ---------------- fused GraphNorm + SiLU + linear via intra-wave LDS transpose ----------------

__global__ void k_nsl(const float* __restrict__ in, __half* __restrict__ out,
                      const float* __restrict__ W, const float* __restrict__ dinv,
                      const float* __restrict__ stats, const float* __restrict__ gamma,
                      const float* __restrict__ beta, const float* __restrict__ alpha,
                      float inv_n, int n) {
    __shared__ float lds[4][UNITS];     // one 256B slot per wave (4 waves/block)
    int lane = threadIdx.x & 63;
    int wib = threadIdx.x >> 6;
    int wpb = blockDim.x >> 6;
    int gwave = blockIdx.x * wpb + wib;
    int nwaves = gridDim.x * wpb;

    float w[UNITS];
#pragma unroll
    for (int k = 0; k < UNITS; ++k) w[k] = W[k * UNITS + lane];

    float m = stats[lane] * inv_n;
    float ex2 = stats[UNITS + lane] * inv_n;
    float al = alpha[lane];
    float var = ex2 - m * m * (2.0f * al - al * al);
    float g = gamma[lane] * rsqrtf(var + GN_EPS);
    float A = g;
    float B = beta[lane] - g * al * m;

    for (int nd = gwave; nd < n; nd += nwaves) {
        int node = __builtin_amdgcn_readfirstlane(nd);
        float hv = in[(size_t)node * UNITS + lane];        // coalesced
        float t = fmaf(hv, A, B);
        t = t / (1.0f + __expf(-t));                        // silu, lane-parallel
        lds[wib][lane] = t;                                 // intra-wave dep only
        float di = dinv[node];
        float a0 = 0.0f, a1 = 0.0f, a2 = 0.0f, a3 = 0.0f;
#pragma unroll
        for (int k = 0; k < UNITS; k += 4) {
            float4 tv = *(const float4*)&lds[wib][k];       // uniform-addr broadcast
            a0 = fmaf(tv.x, w[k + 0], a0);
            a1 = fmaf(tv.y, w[k + 1], a1);
            a2 = fmaf(tv.z, w[k + 2], a2);
            a3 = fmaf(tv.w, w[k + 3], a3);
        }
        float acc = (a0 + a1) + (a2 + a3);
        out[(size_t)node * UNITS + lane] = __float2half(acc * di);
    }
}

// ---------------- fused ParNet layers 1+2: out = relu(t1 + t1@W2 + b2), t1 = relu(in + in@W1 + b1)

__global__ void k_par2(const float* __restrict__ in, float* __restrict__ out,
                       const float* __restrict__ W1, const float* __restrict__ b1,
                       const float* __restrict__ W2, const float* __restrict__ b2, int n) {
    __shared__ float lds[4][UNITS];
    int lane = threadIdx.x & 63;
    int wib = threadIdx.x >> 6;
    int wpb = blockDim.x >> 6;
    int gwave = blockIdx.x * wpb + wib;
    int nwaves = gridDim.x * wpb;

    float w1[UNITS], w2[UNITS];
#pragma unroll
    for (int k = 0; k < UNITS; ++k) w1[k] = W1[k * UNITS + lane];
#pragma unroll
    for (int k = 0; k < UNITS; ++k) w2[k] = W2[k * UNITS + lane];
    float b1j = b1[lane], b2j = b2[lane];

    for (int nd = gwave; nd < n; nd += nwaves) {
        int node = __builtin_amdgcn_readfirstlane(nd);
        const float* __restrict__ row = in + (size_t)node * UNITS;
        float a0 = 0.0f, a1 = 0.0f, a2 = 0.0f, a3 = 0.0f;
#pragma unroll
        for (int k = 0; k < UNITS; k += 4) {
            a0 = fmaf(row[k + 0], w1[k + 0], a0);
            a1 = fmaf(row[k + 1], w1[k + 1], a1);
            a2 = fmaf(row[k + 2], w1[k + 2], a2);
            a3 = fmaf(row[k + 3], w1[k + 3], a3);
        }
        float t1 = fmaxf((a0 + a1) + (a2 + a3) + row[lane] + b1j, 0.0f);  // lane-parallel
        lds[wib][lane] = t1;                                              // intra-wave stage
        a0 = a1 = a2 = a3 = 0.0f;
#pragma unroll
        for (int k = 0; k < UNITS; k += 4) {
            float4 tv = *(const float4*)&lds[wib][k];                     // uniform broadcast
            a0 = fmaf(tv.x, w2[k + 0], a0);
            a1 = fmaf(tv.y, w2[k + 1], a1);
            a2 = fmaf(tv.z, w2[k + 2], a2);
            a3 = fmaf(tv.w, w2[k + 3], a3);
        }
        float t2 = fmaxf((a0 + a1) + (a2 + a3) + t1 + b2j, 0.0f);
        out[(size_t)node * UNITS + lane] = t2;
    }
}

// ---------------- fused ParNet layers 3+4 + head ----------------

__global__ void k_par2h(const float* __restrict__ in,
                        const float* __restrict__ W3, const float* __restrict__ b3,
                        const float* __restrict__ W4, const float* __restrict__ b4,
                        const float* __restrict__ wl, const float* __restrict__ bl,
                        float* __restrict__ out, int n) {
    __shared__ float lds[4][UNITS];
    int lane = threadIdx.x & 63;
    int wib = threadIdx.x >> 6;
    int wpb = blockDim.x >> 6;
    int gwave = blockIdx.x * wpb + wib;
    int nwaves = gridDim.x * wpb;

    float w3[UNITS], w4[UNITS];
#pragma unroll
    for (int k = 0; k < UNITS; ++k) w3[k] = W3[k * UNITS + lane];
#pragma unroll
    for (int k = 0; k < UNITS; ++k) w4[k] = W4[k * UNITS + lane];
    float b3j = b3[lane], b4j = b4[lane];
    float wv = wl[lane];
    float blv = bl[0];

    for (int nd = gwave; nd < n; nd += nwaves) {
        int node = __builtin_amdgcn_readfirstlane(nd);
        const float* __restrict__ row = in + (size_t)node * UNITS;
        float a0 = 0.0f, a1 = 0.0f, a2 = 0.0f, a3 = 0.0f;
#pragma unroll
        for (int k = 0; k < UNITS; k += 4) {
            a0 = fmaf(row[k + 0], w3[k + 0], a0);
            a1 = fmaf(row[k + 1], w3[k + 1], a1);
            a2 = fmaf(row[k + 2], w3[k + 2], a2);
            a3 = fmaf(row[k + 3], w3[k + 3], a3);
        }
        float t3 = fmaxf((a0 + a1) + (a2 + a3) + row[lane] + b3j, 0.0f);
        lds[wib][lane] = t3;
        a0 = a1 = a2 = a3 = 0.0f;
#pragma unroll
        for (int k = 0; k < UNITS; k += 4) {
            float4 tv = *(const float4*)&lds[wib][k];
            a0 = fmaf(tv.x, w4[k + 0], a0);
            a1 = fmaf(tv.y, w4[k + 1], a1);
            a2 = fmaf(tv.z, w4[k + 2], a2);
            a3 = fmaf(tv.w, w4[k + 3], a3);
        }
        float t4 = fmaxf((a0 + a1) + (a2 + a3) + t3 + b4j, 0.0f);
        float p = t4 * wv;
#pragma unroll
        for (int off = 32; off > 0; off >>= 1) p += __shfl_xor(p, off, 64);
        if (lane == 0) out[node] = 1.0f / (1.0f + __expf(-(p + blv)));
    }
}

// ---------------- host launch ----------------

extern "C" void kernel_launch(void* const* d_in, const int* in_sizes, int n_in,
                              void* d_out, int out_size, void* d_ws, size_t ws_size,
                              hipStream_t stream) {
    const float* x = (const float*)d_in[0];
    const int* ei = (const int*)d_in[1];
    const float* conv_w0 = (const float*)d_in[2];
    const float* conv_w = (const float*)d_in[3];
    const float* conv_b = (const float*)d_in[4];
    const float* gn_gamma = (const float*)d_in[5];
    const float* gn_beta = (const float*)d_in[6];
    const float* gn_alpha = (const float*)d_in[7];
    const float* phe_w = (const float*)d_in[8];
    const float* phe_b = (const float*)d_in[9];
    const float* phe_wl = (const float*)d_in[10];
    const float* phe_bl = (const float*)d_in[11];
    const float* heu_w = (const float*)d_in[12];
    const float* heu_b = (const float*)d_in[13];
    const float* heu_wl = (const float*)d_in[14];
    const float* heu_bl = (const float*)d_in[15];

    const int N = in_sizes[0];
    const int E = in_sizes[1] / 2;
    const int NC = N * UNITS;
    const int NCHUNK1024 = (N + 1023) / 1024;
    const int NB = (N + 255) / 256;
    const int EPB = (E + NFILLB - 1) / NFILLB;

    const int* src = ei;
    const int* dstp = ei + E;

    char* w = (char*)d_ws;
    float* dinv = (float*)w;  w += (size_t)N * 4;
    float* h = (float*)w;     w += (size_t)NC * 4;    // fp32 h (gather out, nsl in, ParNet in)
    float* hx = (float*)w;    w += (size_t)NC * 4;    // f16 h2 (embedding) / parnet scratch
    float* h3 = (float*)w;    w += (size_t)NC * 4;    // pairs (CSR build) / parnet scratch
    float* stats = (float*)w; w += (size_t)DEPTH_EMB * 128 * 4;
    int* cnt = (int*)w;       w += (size_t)N * 4;
    int* rowptr = (int*)w;    w += (size_t)(N + 1) * 4;
    int* fillc = (int*)w;     w += (size_t)N * 4;
    int* srcs = (int*)w;      w += (size_t)(E + 16) * 4;
    int* csum = (int*)w;      w += 256 * 4;
    int* coff = (int*)w;      w += 256 * 4;
    int* table = (int*)w;     w += (size_t)MAXNB * NFILLB * 4;
    int* btot = (int*)w;      w += MAXNB * 4;
    int* boff = (int*)w;      w += MAXNB * 4;

    __half* h2 = (__half*)hx;
    unsigned long long* pairs = (unsigned long long*)h3;  // aliases parnet scratch
    float* out = (float*)d_out;

    const int B = 256;
    const int gE = (E + B - 1) / B;
    const int gN = (N + B - 1) / B;
    const int gNC = (NC + B - 1) / B;

    // ---- CSR build (bucketed fill) ----
    hipMemsetAsync(cnt, 0, (size_t)N * 4, stream);
    hipMemsetAsync(fillc, 0, (size_t)N * 4, stream);
    hipMemsetAsync(stats, 0, (size_t)DEPTH_EMB * 128 * 4, stream);
    k_deg<<<gE, B, 0, stream>>>(dstp, cnt, E);
    k_dinv<<<gN, B, 0, stream>>>(cnt, dinv, N);
    k_chunksum<<<NCHUNK1024, 256, 0, stream>>>(cnt, csum, N);
    k_scansum<<<1, 256, 0, stream>>>(csum, coff, rowptr, NCHUNK1024);
    k_scanfinal<<<NCHUNK1024, 1024, 0, stream>>>(cnt, coff, rowptr, N);
    k_bcount<<<NFILLB, 256, 0, stream>>>(dstp, table, E, NB, EPB);
    k_bscan<<<NB, NFILLB, 0, stream>>>(table, btot);
    k_boffscan<<<1, MAXNB, 0, stream>>>(btot, boff, NB);
    k_bscatter<<<NFILLB, 256, 0, stream>>>(src, dstp, table, boff, pairs, E, NB, EPB);
    k_pfill<<<2048, B, 0, stream>>>(pairs, rowptr, fillc, srcs, E);

    // ---- GCN embedding ----
    k_l0<<<gNC, B, 0, stream>>>(x, conv_w0, dinv, h2, N);
    for (int i = 0; i < DEPTH_EMB; ++i) {
        float* st = stats + (size_t)i * 128;
        if (i < DEPTH_EMB - 1) {
            k_gather<1><<<2048, B, 0, stream>>>(h2, h, rowptr, srcs, dinv,
                                                conv_b + (size_t)i * UNITS, st, N);
            k_nsl<<<2048, B, 0, stream>>>(h, h2, conv_w + (size_t)i * UNITS * UNITS,
                                          dinv, st,
                                          gn_gamma + (size_t)i * UNITS,
                                          gn_beta + (size_t)i * UNITS,
                                          gn_alpha + (size_t)i * UNITS,
                                          1.0f / (float)N, N);
        } else {
            k_gather<0><<<2048, B, 0, stream>>>(h2, h, rowptr, srcs, dinv,
                                                conv_b + (size_t)i * UNITS, st, N);
        }
    }

    // ---- ParNet heads: 2 fused dispatches per head ----
    for (int head = 0; head < 2; ++head) {
        const float* wsrc = head == 0 ? phe_w : heu_w;
        const float* bsrc = head == 0 ? phe_b : heu_b;
        const float* wl = head == 0 ? phe_wl : heu_wl;
        const float* bl = head == 0 ? phe_bl : heu_bl;
        float* o = out + (size_t)head * N;

        k_par2<<<2048, B, 0, stream>>>(h, h3, wsrc, bsrc,
                                       wsrc + (size_t)1 * UNITS * UNITS,
                                       bsrc + (size_t)1 * UNITS, N);
        k_par2h<<<2048, B, 0, stream>>>(h3,
                                        wsrc + (size_t)2 * UNITS * UNITS,
                                        bsrc + (size_t)2 * UNITS,
                                        wsrc + (size_t)3 * UNITS * UNITS,
                                        bsrc + (size_t)3 * UNITS,
                                        wl, bl, o, N);
    }
}

// Round 18
// 1601.710 us; speedup vs baseline: 1.1979x; 1.1979x over previous
//
#include <hip/hip_runtime.h>
#include <hip/hip_bf16.h>
#include <hip/hip_fp16.h>
#include <math.h>

#define UNITS 64
#define DEPTH_EMB 12
#define DEPTH_PAR 5
#define GN_EPS 1e-5f
#define NFILLB 256          // blocks in bucketed fill
#define MAXNB 512           // max buckets (N <= 131072)

// ---------------- CSR build ----------------

__global__ void k_deg(const int* __restrict__ dst, int* __restrict__ cnt, int E) {
    int e = blockIdx.x * blockDim.x + threadIdx.x;
    if (e < E) atomicAdd(&cnt[dst[e]], 1);
}

__global__ void k_dinv(const int* __restrict__ cnt, float* __restrict__ dinv, int n) {
    int i = blockIdx.x * blockDim.x + threadIdx.x;
    if (i < n) dinv[i] = rsqrtf(1.0f + (float)cnt[i]);
}

__global__ void k_chunksum(const int* __restrict__ cnt, int* __restrict__ csum, int n) {
    __shared__ int sd[256];
    int base = blockIdx.x * 1024;
    int s = 0;
    for (int i = threadIdx.x; i < 1024; i += 256) {
        int idx = base + i;
        if (idx < n) s += cnt[idx];
    }
    sd[threadIdx.x] = s;
    __syncthreads();
    for (int off = 128; off > 0; off >>= 1) {
        if (threadIdx.x < off) sd[threadIdx.x] += sd[threadIdx.x + off];
        __syncthreads();
    }
    if (threadIdx.x == 0) csum[blockIdx.x] = sd[0];
}

__global__ void k_scansum(const int* __restrict__ csum, int* __restrict__ coff,
                          int* __restrict__ rowptr, int nchunks) {
    __shared__ int sd[256];
    int tid = threadIdx.x;
    int v = (tid < nchunks) ? csum[tid] : 0;
    sd[tid] = v;
    __syncthreads();
    for (int off = 1; off < 256; off <<= 1) {
        int t = (tid >= off) ? sd[tid - off] : 0;
        __syncthreads();
        sd[tid] += t;
        __syncthreads();
    }
    if (tid < nchunks) coff[tid] = sd[tid] - v;
    if (tid == 0) rowptr[0] = 0;
}

__global__ void k_scanfinal(const int* __restrict__ cnt, const int* __restrict__ coff,
                            int* __restrict__ rowptr, int n) {
    __shared__ int sd[1024];
    int base = blockIdx.x * 1024;
    int tid = threadIdx.x;
    int idx = base + tid;
    int v = (idx < n) ? cnt[idx] : 0;
    sd[tid] = v;
    __syncthreads();
    for (int off = 1; off < 1024; off <<= 1) {
        int t = (tid >= off) ? sd[tid - off] : 0;
        __syncthreads();
        sd[tid] += t;
        __syncthreads();
    }
    if (idx < n) rowptr[idx + 1] = coff[blockIdx.x] + sd[tid];
}

// ---------------- bucketed fill ----------------

__global__ void k_bcount(const int* __restrict__ dst, int* __restrict__ table,
                         int E, int nb, int epb) {
    __shared__ int hist[MAXNB];
    int tid = threadIdx.x;
    for (int i = tid; i < nb; i += 256) hist[i] = 0;
    __syncthreads();
    int e0 = blockIdx.x * epb;
    int e1 = min(e0 + epb, E);
    for (int e = e0 + tid; e < e1; e += 256) atomicAdd(&hist[dst[e] >> 8], 1);
    __syncthreads();
    for (int i = tid; i < nb; i += 256) table[i * NFILLB + blockIdx.x] = hist[i];
}

__global__ void k_bscan(int* __restrict__ table, int* __restrict__ btot) {
    __shared__ int sd[NFILLB];
    int b = blockIdx.x;
    int tid = threadIdx.x;
    int v = table[b * NFILLB + tid];
    sd[tid] = v;
    __syncthreads();
    for (int off = 1; off < NFILLB; off <<= 1) {
        int t = (tid >= off) ? sd[tid - off] : 0;
        __syncthreads();
        sd[tid] += t;
        __syncthreads();
    }
    table[b * NFILLB + tid] = sd[tid] - v;
    if (tid == NFILLB - 1) btot[b] = sd[NFILLB - 1];
}

__global__ void k_boffscan(const int* __restrict__ btot, int* __restrict__ boff, int nb) {
    __shared__ int sd[MAXNB];
    int tid = threadIdx.x;
    int v = (tid < nb) ? btot[tid] : 0;
    sd[tid] = v;
    __syncthreads();
    for (int off = 1; off < MAXNB; off <<= 1) {
        int t = (tid >= off) ? sd[tid - off] : 0;
        __syncthreads();
        sd[tid] += t;
        __syncthreads();
    }
    if (tid < nb) boff[tid] = sd[tid] - v;
}

__global__ void k_bscatter(const int* __restrict__ src, const int* __restrict__ dst,
                           const int* __restrict__ table, const int* __restrict__ boff,
                           unsigned long long* __restrict__ pairs, int E, int nb, int epb) {
    __shared__ int hist[MAXNB];
    int tid = threadIdx.x;
    for (int i = tid; i < nb; i += 256) hist[i] = 0;
    __syncthreads();
    int e0 = blockIdx.x * epb;
    int e1 = min(e0 + epb, E);
    for (int e = e0 + tid; e < e1; e += 256) {
        int d = dst[e];
        int b = d >> 8;
        int local = atomicAdd(&hist[b], 1);
        int p = boff[b] + table[b * NFILLB + blockIdx.x] + local;
        pairs[p] = ((unsigned long long)(unsigned)d << 32) | (unsigned)src[e];
    }
}

__global__ void k_pfill(const unsigned long long* __restrict__ pairs,
                        const int* __restrict__ rowptr, int* __restrict__ fillc,
                        int* __restrict__ srcs, int E) {
    int stride = gridDim.x * blockDim.x;
    for (int idx = blockIdx.x * blockDim.x + threadIdx.x; idx < E; idx += stride) {
        unsigned long long pr = pairs[idx];
        int s = (int)(pr & 0xffffffffu);
        int d = (int)(pr >> 32);
        int p = rowptr[d] + atomicAdd(&fillc[d], 1);
        srcs[p] = s;
    }
}

// ---------------- layer 0: h2 = f16(dinv * (x @ w0)), row-major [N][64] ----------------

__global__ void k_l0(const float* __restrict__ x, const float* __restrict__ w0,
                     const float* __restrict__ dinv, __half* __restrict__ h2, int n) {
    int gid = blockIdx.x * blockDim.x + threadIdx.x;
    if (gid >= n * UNITS) return;
    int node = gid >> 6, c = gid & 63;
    h2[gid] = __float2half(x[node] * w0[c] * dinv[node]);
}

// ---------------- gather: h[d] = dinv[d]*(sum srcs rows + own row) + b ----------------

template <int DO_STATS>
__global__ void k_gather(const __half* __restrict__ h2, float* __restrict__ h,
                         const int* __restrict__ rowptr, const int* __restrict__ srcs,
                         const float* __restrict__ dinv, const float* __restrict__ b,
                         float* __restrict__ stats, int n) {
    int lane = threadIdx.x & 63;
    int wib = threadIdx.x >> 6;
    int wpb = blockDim.x >> 6;
    int gwave = blockIdx.x * wpb + wib;
    int nwaves = gridDim.x * wpb;
    float bj = b[lane];
    float s1 = 0.0f, s2 = 0.0f;

    for (int nd = gwave; nd < n; nd += nwaves) {
        int node = __builtin_amdgcn_readfirstlane(nd);
        int beg = rowptr[node], end = rowptr[node + 1];
        float di = dinv[node];
        float acc0 = __half2float(h2[(size_t)node * UNITS + lane]);   // self row
        float acc1 = 0.0f, acc2 = 0.0f, acc3 = 0.0f;
        int j = beg;
        for (; j + 8 <= end; j += 8) {
            int i0 = srcs[j + 0], i1 = srcs[j + 1], i2 = srcs[j + 2], i3 = srcs[j + 3];
            int i4 = srcs[j + 4], i5 = srcs[j + 5], i6 = srcs[j + 6], i7 = srcs[j + 7];
            float v0 = __half2float(h2[(size_t)i0 * UNITS + lane]);
            float v1 = __half2float(h2[(size_t)i1 * UNITS + lane]);
            float v2 = __half2float(h2[(size_t)i2 * UNITS + lane]);
            float v3 = __half2float(h2[(size_t)i3 * UNITS + lane]);
            float v4 = __half2float(h2[(size_t)i4 * UNITS + lane]);
            float v5 = __half2float(h2[(size_t)i5 * UNITS + lane]);
            float v6 = __half2float(h2[(size_t)i6 * UNITS + lane]);
            float v7 = __half2float(h2[(size_t)i7 * UNITS + lane]);
            acc0 += v0; acc1 += v1; acc2 += v2; acc3 += v3;
            acc0 += v4; acc1 += v5; acc2 += v6; acc3 += v7;
        }
        for (; j + 4 <= end; j += 4) {
            int i0 = srcs[j + 0], i1 = srcs[j + 1], i2 = srcs[j + 2], i3 = srcs[j + 3];
            float v0 = __half2float(h2[(size_t)i0 * UNITS + lane]);
            float v1 = __half2float(h2[(size_t)i1 * UNITS + lane]);
            float v2 = __half2float(h2[(size_t)i2 * UNITS + lane]);
            float v3 = __half2float(h2[(size_t)i3 * UNITS + lane]);
            acc0 += v0; acc1 += v1; acc2 += v2; acc3 += v3;
        }
        for (; j < end; ++j) acc0 += __half2float(h2[(size_t)srcs[j] * UNITS + lane]);
        float acc = (acc0 + acc1) + (acc2 + acc3);
        float hv = fmaf(acc, di, bj);
        h[(size_t)node * UNITS + lane] = hv;
        if (DO_STATS) {
            s1 += hv;
            s2 = fmaf(hv, hv, s2);
        }
    }

    if (DO_STATS) {
        __shared__ float sd[2][4][UNITS];
        sd[0][wib][lane] = s1;
        sd[1][wib][lane] = s2;
        __syncthreads();
        if (threadIdx.x < UNITS) {
            float a1 = 0.0f, a2 = 0.0f;
            for (int r = 0; r < wpb; ++r) {
                a1 += sd[0][r][lane];
                a2 += sd[1][r][lane];
            }
            atomicAdd(&stats[lane], a1);
            atomicAdd(&stats[UNITS + lane], a2);
        }
    }
}

// ---------------- fused GraphNorm + SiLU + linear via intra-wave LDS transpose ----------------

__global__ void k_nsl(const float* __restrict__ in, __half* __restrict__ out,
                      const float* __restrict__ W, const float* __restrict__ dinv,
                      const float* __restrict__ stats, const float* __restrict__ gamma,
                      const float* __restrict__ beta, const float* __restrict__ alpha,
                      float inv_n, int n) {
    __shared__ float lds[4][UNITS];     // one 256B slot per wave (4 waves/block)
    int lane = threadIdx.x & 63;
    int wib = threadIdx.x >> 6;
    int wpb = blockDim.x >> 6;
    int gwave = blockIdx.x * wpb + wib;
    int nwaves = gridDim.x * wpb;

    float w[UNITS];
#pragma unroll
    for (int k = 0; k < UNITS; ++k) w[k] = W[k * UNITS + lane];

    float m = stats[lane] * inv_n;
    float ex2 = stats[UNITS + lane] * inv_n;
    float al = alpha[lane];
    float var = ex2 - m * m * (2.0f * al - al * al);
    float g = gamma[lane] * rsqrtf(var + GN_EPS);
    float A = g;
    float B = beta[lane] - g * al * m;

    for (int nd = gwave; nd < n; nd += nwaves) {
        int node = __builtin_amdgcn_readfirstlane(nd);
        float hv = in[(size_t)node * UNITS + lane];        // coalesced
        float t = fmaf(hv, A, B);
        t = t / (1.0f + __expf(-t));                        // silu, lane-parallel
        lds[wib][lane] = t;                                 // intra-wave dep only
        float di = dinv[node];
        float a0 = 0.0f, a1 = 0.0f, a2 = 0.0f, a3 = 0.0f;
#pragma unroll
        for (int k = 0; k < UNITS; k += 4) {
            float4 tv = *(const float4*)&lds[wib][k];       // uniform-addr broadcast
            a0 = fmaf(tv.x, w[k + 0], a0);
            a1 = fmaf(tv.y, w[k + 1], a1);
            a2 = fmaf(tv.z, w[k + 2], a2);
            a3 = fmaf(tv.w, w[k + 3], a3);
        }
        float acc = (a0 + a1) + (a2 + a3);
        out[(size_t)node * UNITS + lane] = __float2half(acc * di);
    }
}

// ---------------- fused ParNet layers 1+2 (launch_bounds lifts VGPR cap; no spill) ----------------

__global__ __launch_bounds__(256, 2)
void k_par2(const float* __restrict__ in, float* __restrict__ out,
            const float* __restrict__ W1, const float* __restrict__ b1,
            const float* __restrict__ W2, const float* __restrict__ b2, int n) {
    __shared__ float lds[4][UNITS];
    int lane = threadIdx.x & 63;
    int wib = threadIdx.x >> 6;
    int wpb = blockDim.x >> 6;
    int gwave = blockIdx.x * wpb + wib;
    int nwaves = gridDim.x * wpb;

    float w1[UNITS], w2[UNITS];
#pragma unroll
    for (int k = 0; k < UNITS; ++k) w1[k] = W1[k * UNITS + lane];
#pragma unroll
    for (int k = 0; k < UNITS; ++k) w2[k] = W2[k * UNITS + lane];
    float b1j = b1[lane], b2j = b2[lane];

    for (int nd = gwave; nd < n; nd += nwaves) {
        int node = __builtin_amdgcn_readfirstlane(nd);
        const float* __restrict__ row = in + (size_t)node * UNITS;
        float a0 = 0.0f, a1 = 0.0f, a2 = 0.0f, a3 = 0.0f;
#pragma unroll
        for (int k = 0; k < UNITS; k += 4) {
            a0 = fmaf(row[k + 0], w1[k + 0], a0);
            a1 = fmaf(row[k + 1], w1[k + 1], a1);
            a2 = fmaf(row[k + 2], w1[k + 2], a2);
            a3 = fmaf(row[k + 3], w1[k + 3], a3);
        }
        float t1 = fmaxf((a0 + a1) + (a2 + a3) + row[lane] + b1j, 0.0f);  // lane-parallel
        lds[wib][lane] = t1;                                              // intra-wave stage
        a0 = a1 = a2 = a3 = 0.0f;
#pragma unroll
        for (int k = 0; k < UNITS; k += 4) {
            float4 tv = *(const float4*)&lds[wib][k];                     // uniform broadcast
            a0 = fmaf(tv.x, w2[k + 0], a0);
            a1 = fmaf(tv.y, w2[k + 1], a1);
            a2 = fmaf(tv.z, w2[k + 2], a2);
            a3 = fmaf(tv.w, w2[k + 3], a3);
        }
        float t2 = fmaxf((a0 + a1) + (a2 + a3) + t1 + b2j, 0.0f);
        out[(size_t)node * UNITS + lane] = t2;
    }
}

// ---------------- fused ParNet layers 3+4 + head ----------------

__global__ __launch_bounds__(256, 2)
void k_par2h(const float* __restrict__ in,
             const float* __restrict__ W3, const float* __restrict__ b3,
             const float* __restrict__ W4, const float* __restrict__ b4,
             const float* __restrict__ wl, const float* __restrict__ bl,
             float* __restrict__ out, int n) {
    __shared__ float lds[4][UNITS];
    int lane = threadIdx.x & 63;
    int wib = threadIdx.x >> 6;
    int wpb = blockDim.x >> 6;
    int gwave = blockIdx.x * wpb + wib;
    int nwaves = gridDim.x * wpb;

    float w3[UNITS], w4[UNITS];
#pragma unroll
    for (int k = 0; k < UNITS; ++k) w3[k] = W3[k * UNITS + lane];
#pragma unroll
    for (int k = 0; k < UNITS; ++k) w4[k] = W4[k * UNITS + lane];
    float b3j = b3[lane], b4j = b4[lane];
    float wv = wl[lane];
    float blv = bl[0];

    for (int nd = gwave; nd < n; nd += nwaves) {
        int node = __builtin_amdgcn_readfirstlane(nd);
        const float* __restrict__ row = in + (size_t)node * UNITS;
        float a0 = 0.0f, a1 = 0.0f, a2 = 0.0f, a3 = 0.0f;
#pragma unroll
        for (int k = 0; k < UNITS; k += 4) {
            a0 = fmaf(row[k + 0], w3[k + 0], a0);
            a1 = fmaf(row[k + 1], w3[k + 1], a1);
            a2 = fmaf(row[k + 2], w3[k + 2], a2);
            a3 = fmaf(row[k + 3], w3[k + 3], a3);
        }
        float t3 = fmaxf((a0 + a1) + (a2 + a3) + row[lane] + b3j, 0.0f);
        lds[wib][lane] = t3;
        a0 = a1 = a2 = a3 = 0.0f;
#pragma unroll
        for (int k = 0; k < UNITS; k += 4) {
            float4 tv = *(const float4*)&lds[wib][k];
            a0 = fmaf(tv.x, w4[k + 0], a0);
            a1 = fmaf(tv.y, w4[k + 1], a1);
            a2 = fmaf(tv.z, w4[k + 2], a2);
            a3 = fmaf(tv.w, w4[k + 3], a3);
        }
        float t4 = fmaxf((a0 + a1) + (a2 + a3) + t3 + b4j, 0.0f);
        float p = t4 * wv;
#pragma unroll
        for (int off = 32; off > 0; off >>= 1) p += __shfl_xor(p, off, 64);
        if (lane == 0) out[node] = 1.0f / (1.0f + __expf(-(p + blv)));
    }
}

// ---------------- host launch ----------------

extern "C" void kernel_launch(void* const* d_in, const int* in_sizes, int n_in,
                              void* d_out, int out_size, void* d_ws, size_t ws_size,
                              hipStream_t stream) {
    const float* x = (const float*)d_in[0];
    const int* ei = (const int*)d_in[1];
    const float* conv_w0 = (const float*)d_in[2];
    const float* conv_w = (const float*)d_in[3];
    const float* conv_b = (const float*)d_in[4];
    const float* gn_gamma = (const float*)d_in[5];
    const float* gn_beta = (const float*)d_in[6];
    const float* gn_alpha = (const float*)d_in[7];
    const float* phe_w = (const float*)d_in[8];
    const float* phe_b = (const float*)d_in[9];
    const float* phe_wl = (const float*)d_in[10];
    const float* phe_bl = (const float*)d_in[11];
    const float* heu_w = (const float*)d_in[12];
    const float* heu_b = (const float*)d_in[13];
    const float* heu_wl = (const float*)d_in[14];
    const float* heu_bl = (const float*)d_in[15];

    const int N = in_sizes[0];
    const int E = in_sizes[1] / 2;
    const int NC = N * UNITS;
    const int NCHUNK1024 = (N + 1023) / 1024;
    const int NB = (N + 255) / 256;
    const int EPB = (E + NFILLB - 1) / NFILLB;

    const int* src = ei;
    const int* dstp = ei + E;

    char* w = (char*)d_ws;
    float* dinv = (float*)w;  w += (size_t)N * 4;
    float* h = (float*)w;     w += (size_t)NC * 4;    // fp32 h (gather out, nsl in, ParNet in)
    float* hx = (float*)w;    w += (size_t)NC * 4;    // f16 h2 (embedding) / parnet scratch
    float* h3 = (float*)w;    w += (size_t)NC * 4;    // pairs (CSR build) / parnet scratch
    float* stats = (float*)w; w += (size_t)DEPTH_EMB * 128 * 4;
    int* cnt = (int*)w;       w += (size_t)N * 4;
    int* rowptr = (int*)w;    w += (size_t)(N + 1) * 4;
    int* fillc = (int*)w;     w += (size_t)N * 4;
    int* srcs = (int*)w;      w += (size_t)(E + 16) * 4;
    int* csum = (int*)w;      w += 256 * 4;
    int* coff = (int*)w;      w += 256 * 4;
    int* table = (int*)w;     w += (size_t)MAXNB * NFILLB * 4;
    int* btot = (int*)w;      w += MAXNB * 4;
    int* boff = (int*)w;      w += MAXNB * 4;

    __half* h2 = (__half*)hx;
    unsigned long long* pairs = (unsigned long long*)h3;  // aliases parnet scratch
    float* out = (float*)d_out;

    const int B = 256;
    const int gE = (E + B - 1) / B;
    const int gN = (N + B - 1) / B;
    const int gNC = (NC + B - 1) / B;

    // ---- CSR build (bucketed fill) ----
    hipMemsetAsync(cnt, 0, (size_t)N * 4, stream);
    hipMemsetAsync(fillc, 0, (size_t)N * 4, stream);
    hipMemsetAsync(stats, 0, (size_t)DEPTH_EMB * 128 * 4, stream);
    k_deg<<<gE, B, 0, stream>>>(dstp, cnt, E);
    k_dinv<<<gN, B, 0, stream>>>(cnt, dinv, N);
    k_chunksum<<<NCHUNK1024, 256, 0, stream>>>(cnt, csum, N);
    k_scansum<<<1, 256, 0, stream>>>(csum, coff, rowptr, NCHUNK1024);
    k_scanfinal<<<NCHUNK1024, 1024, 0, stream>>>(cnt, coff, rowptr, N);
    k_bcount<<<NFILLB, 256, 0, stream>>>(dstp, table, E, NB, EPB);
    k_bscan<<<NB, NFILLB, 0, stream>>>(table, btot);
    k_boffscan<<<1, MAXNB, 0, stream>>>(btot, boff, NB);
    k_bscatter<<<NFILLB, 256, 0, stream>>>(src, dstp, table, boff, pairs, E, NB, EPB);
    k_pfill<<<2048, B, 0, stream>>>(pairs, rowptr, fillc, srcs, E);

    // ---- GCN embedding ----
    k_l0<<<gNC, B, 0, stream>>>(x, conv_w0, dinv, h2, N);
    for (int i = 0; i < DEPTH_EMB; ++i) {
        float* st = stats + (size_t)i * 128;
        if (i < DEPTH_EMB - 1) {
            k_gather<1><<<2048, B, 0, stream>>>(h2, h, rowptr, srcs, dinv,
                                                conv_b + (size_t)i * UNITS, st, N);
            k_nsl<<<2048, B, 0, stream>>>(h, h2, conv_w + (size_t)i * UNITS * UNITS,
                                          dinv, st,
                                          gn_gamma + (size_t)i * UNITS,
                                          gn_beta + (size_t)i * UNITS,
                                          gn_alpha + (size_t)i * UNITS,
                                          1.0f / (float)N, N);
        } else {
            k_gather<0><<<2048, B, 0, stream>>>(h2, h, rowptr, srcs, dinv,
                                                conv_b + (size_t)i * UNITS, st, N);
        }
    }

    // ---- ParNet heads: 2 fused dispatches per head ----
    for (int head = 0; head < 2; ++head) {
        const float* wsrc = head == 0 ? phe_w : heu_w;
        const float* bsrc = head == 0 ? phe_b : heu_b;
        const float* wl = head == 0 ? phe_wl : heu_wl;
        const float* bl = head == 0 ? phe_bl : heu_bl;
        float* o = out + (size_t)head * N;

        k_par2<<<2048, B, 0, stream>>>(h, h3, wsrc, bsrc,
                                       wsrc + (size_t)1 * UNITS * UNITS,
                                       bsrc + (size_t)1 * UNITS, N);
        k_par2h<<<2048, B, 0, stream>>>(h3,
                                        wsrc + (size_t)2 * UNITS * UNITS,
                                        bsrc + (size_t)2 * UNITS,
                                        wsrc + (size_t)3 * UNITS * UNITS,
                                        bsrc + (size_t)3 * UNITS,
                                        wl, bl, o, N);
    }
}

// Round 19
// 1532.974 us; speedup vs baseline: 1.2516x; 1.0448x over previous
//
#include <hip/hip_runtime.h>
#include <hip/hip_bf16.h>
#include <hip/hip_fp16.h>
#include <math.h>

#define UNITS 64
#define DEPTH_EMB 12
#define DEPTH_PAR 5
#define GN_EPS 1e-5f
#define NFILLB 256          // blocks in bucketed fill
#define MAXNB 512           // max buckets (N <= 131072)

// ---------------- CSR build ----------------

__global__ void k_deg(const int* __restrict__ dst, int* __restrict__ cnt, int E) {
    int e = blockIdx.x * blockDim.x + threadIdx.x;
    if (e < E) atomicAdd(&cnt[dst[e]], 1);
}

__global__ void k_dinv(const int* __restrict__ cnt, float* __restrict__ dinv, int n) {
    int i = blockIdx.x * blockDim.x + threadIdx.x;
    if (i < n) dinv[i] = rsqrtf(1.0f + (float)cnt[i]);
}

__global__ void k_chunksum(const int* __restrict__ cnt, int* __restrict__ csum, int n) {
    __shared__ int sd[256];
    int base = blockIdx.x * 1024;
    int s = 0;
    for (int i = threadIdx.x; i < 1024; i += 256) {
        int idx = base + i;
        if (idx < n) s += cnt[idx];
    }
    sd[threadIdx.x] = s;
    __syncthreads();
    for (int off = 128; off > 0; off >>= 1) {
        if (threadIdx.x < off) sd[threadIdx.x] += sd[threadIdx.x + off];
        __syncthreads();
    }
    if (threadIdx.x == 0) csum[blockIdx.x] = sd[0];
}

__global__ void k_scansum(const int* __restrict__ csum, int* __restrict__ coff,
                          int* __restrict__ rowptr, int nchunks) {
    __shared__ int sd[256];
    int tid = threadIdx.x;
    int v = (tid < nchunks) ? csum[tid] : 0;
    sd[tid] = v;
    __syncthreads();
    for (int off = 1; off < 256; off <<= 1) {
        int t = (tid >= off) ? sd[tid - off] : 0;
        __syncthreads();
        sd[tid] += t;
        __syncthreads();
    }
    if (tid < nchunks) coff[tid] = sd[tid] - v;
    if (tid == 0) rowptr[0] = 0;
}

__global__ void k_scanfinal(const int* __restrict__ cnt, const int* __restrict__ coff,
                            int* __restrict__ rowptr, int n) {
    __shared__ int sd[1024];
    int base = blockIdx.x * 1024;
    int tid = threadIdx.x;
    int idx = base + tid;
    int v = (idx < n) ? cnt[idx] : 0;
    sd[tid] = v;
    __syncthreads();
    for (int off = 1; off < 1024; off <<= 1) {
        int t = (tid >= off) ? sd[tid - off] : 0;
        __syncthreads();
        sd[tid] += t;
        __syncthreads();
    }
    if (idx < n) rowptr[idx + 1] = coff[blockIdx.x] + sd[tid];
}

// ---------------- bucketed fill ----------------

__global__ void k_bcount(const int* __restrict__ dst, int* __restrict__ table,
                         int E, int nb, int epb) {
    __shared__ int hist[MAXNB];
    int tid = threadIdx.x;
    for (int i = tid; i < nb; i += 256) hist[i] = 0;
    __syncthreads();
    int e0 = blockIdx.x * epb;
    int e1 = min(e0 + epb, E);
    for (int e = e0 + tid; e < e1; e += 256) atomicAdd(&hist[dst[e] >> 8], 1);
    __syncthreads();
    for (int i = tid; i < nb; i += 256) table[i * NFILLB + blockIdx.x] = hist[i];
}

__global__ void k_bscan(int* __restrict__ table, int* __restrict__ btot) {
    __shared__ int sd[NFILLB];
    int b = blockIdx.x;
    int tid = threadIdx.x;
    int v = table[b * NFILLB + tid];
    sd[tid] = v;
    __syncthreads();
    for (int off = 1; off < NFILLB; off <<= 1) {
        int t = (tid >= off) ? sd[tid - off] : 0;
        __syncthreads();
        sd[tid] += t;
        __syncthreads();
    }
    table[b * NFILLB + tid] = sd[tid] - v;
    if (tid == NFILLB - 1) btot[b] = sd[NFILLB - 1];
}

__global__ void k_boffscan(const int* __restrict__ btot, int* __restrict__ boff, int nb) {
    __shared__ int sd[MAXNB];
    int tid = threadIdx.x;
    int v = (tid < nb) ? btot[tid] : 0;
    sd[tid] = v;
    __syncthreads();
    for (int off = 1; off < MAXNB; off <<= 1) {
        int t = (tid >= off) ? sd[tid - off] : 0;
        __syncthreads();
        sd[tid] += t;
        __syncthreads();
    }
    if (tid < nb) boff[tid] = sd[tid] - v;
}

__global__ void k_bscatter(const int* __restrict__ src, const int* __restrict__ dst,
                           const int* __restrict__ table, const int* __restrict__ boff,
                           unsigned long long* __restrict__ pairs, int E, int nb, int epb) {
    __shared__ int hist[MAXNB];
    int tid = threadIdx.x;
    for (int i = tid; i < nb; i += 256) hist[i] = 0;
    __syncthreads();
    int e0 = blockIdx.x * epb;
    int e1 = min(e0 + epb, E);
    for (int e = e0 + tid; e < e1; e += 256) {
        int d = dst[e];
        int b = d >> 8;
        int local = atomicAdd(&hist[b], 1);
        int p = boff[b] + table[b * NFILLB + blockIdx.x] + local;
        pairs[p] = ((unsigned long long)(unsigned)d << 32) | (unsigned)src[e];
    }
}

__global__ void k_pfill(const unsigned long long* __restrict__ pairs,
                        const int* __restrict__ rowptr, int* __restrict__ fillc,
                        int* __restrict__ srcs, int E) {
    int stride = gridDim.x * blockDim.x;
    for (int idx = blockIdx.x * blockDim.x + threadIdx.x; idx < E; idx += stride) {
        unsigned long long pr = pairs[idx];
        int s = (int)(pr & 0xffffffffu);
        int d = (int)(pr >> 32);
        int p = rowptr[d] + atomicAdd(&fillc[d], 1);
        srcs[p] = s;
    }
}

// ---------------- layer 0: h2 = f16(dinv * (x @ w0)), row-major [N][64] ----------------

__global__ void k_l0(const float* __restrict__ x, const float* __restrict__ w0,
                     const float* __restrict__ dinv, __half* __restrict__ h2, int n) {
    int gid = blockIdx.x * blockDim.x + threadIdx.x;
    if (gid >= n * UNITS) return;
    int node = gid >> 6, c = gid & 63;
    h2[gid] = __float2half(x[node] * w0[c] * dinv[node]);
}

// ---------------- gather: h[d] = dinv[d]*(sum srcs rows + own row) + b ----------------

template <int DO_STATS>
__global__ void k_gather(const __half* __restrict__ h2, float* __restrict__ h,
                         const int* __restrict__ rowptr, const int* __restrict__ srcs,
                         const float* __restrict__ dinv, const float* __restrict__ b,
                         float* __restrict__ stats, int n) {
    int lane = threadIdx.x & 63;
    int wib = threadIdx.x >> 6;
    int wpb = blockDim.x >> 6;
    int gwave = blockIdx.x * wpb + wib;
    int nwaves = gridDim.x * wpb;
    float bj = b[lane];
    float s1 = 0.0f, s2 = 0.0f;

    for (int nd = gwave; nd < n; nd += nwaves) {
        int node = __builtin_amdgcn_readfirstlane(nd);
        int beg = rowptr[node], end = rowptr[node + 1];
        float di = dinv[node];
        float acc0 = __half2float(h2[(size_t)node * UNITS + lane]);   // self row
        float acc1 = 0.0f, acc2 = 0.0f, acc3 = 0.0f;
        int j = beg;
        for (; j + 8 <= end; j += 8) {
            int i0 = srcs[j + 0], i1 = srcs[j + 1], i2 = srcs[j + 2], i3 = srcs[j + 3];
            int i4 = srcs[j + 4], i5 = srcs[j + 5], i6 = srcs[j + 6], i7 = srcs[j + 7];
            float v0 = __half2float(h2[(size_t)i0 * UNITS + lane]);
            float v1 = __half2float(h2[(size_t)i1 * UNITS + lane]);
            float v2 = __half2float(h2[(size_t)i2 * UNITS + lane]);
            float v3 = __half2float(h2[(size_t)i3 * UNITS + lane]);
            float v4 = __half2float(h2[(size_t)i4 * UNITS + lane]);
            float v5 = __half2float(h2[(size_t)i5 * UNITS + lane]);
            float v6 = __half2float(h2[(size_t)i6 * UNITS + lane]);
            float v7 = __half2float(h2[(size_t)i7 * UNITS + lane]);
            acc0 += v0; acc1 += v1; acc2 += v2; acc3 += v3;
            acc0 += v4; acc1 += v5; acc2 += v6; acc3 += v7;
        }
        for (; j + 4 <= end; j += 4) {
            int i0 = srcs[j + 0], i1 = srcs[j + 1], i2 = srcs[j + 2], i3 = srcs[j + 3];
            float v0 = __half2float(h2[(size_t)i0 * UNITS + lane]);
            float v1 = __half2float(h2[(size_t)i1 * UNITS + lane]);
            float v2 = __half2float(h2[(size_t)i2 * UNITS + lane]);
            float v3 = __half2float(h2[(size_t)i3 * UNITS + lane]);
            acc0 += v0; acc1 += v1; acc2 += v2; acc3 += v3;
        }
        for (; j < end; ++j) acc0 += __half2float(h2[(size_t)srcs[j] * UNITS + lane]);
        float acc = (acc0 + acc1) + (acc2 + acc3);
        float hv = fmaf(acc, di, bj);
        h[(size_t)node * UNITS + lane] = hv;
        if (DO_STATS) {
            s1 += hv;
            s2 = fmaf(hv, hv, s2);
        }
    }

    if (DO_STATS) {
        __shared__ float sd[2][4][UNITS];
        sd[0][wib][lane] = s1;
        sd[1][wib][lane] = s2;
        __syncthreads();
        if (threadIdx.x < UNITS) {
            float a1 = 0.0f, a2 = 0.0f;
            for (int r = 0; r < wpb; ++r) {
                a1 += sd[0][r][lane];
                a2 += sd[1][r][lane];
            }
            atomicAdd(&stats[lane], a1);
            atomicAdd(&stats[UNITS + lane], a2);
        }
    }
}

// ---------------- fused GraphNorm + SiLU + linear via intra-wave LDS transpose ----------------

__global__ void k_nsl(const float* __restrict__ in, __half* __restrict__ out,
                      const float* __restrict__ W, const float* __restrict__ dinv,
                      const float* __restrict__ stats, const float* __restrict__ gamma,
                      const float* __restrict__ beta, const float* __restrict__ alpha,
                      float inv_n, int n) {
    __shared__ float lds[4][UNITS];     // one 256B slot per wave (4 waves/block)
    int lane = threadIdx.x & 63;
    int wib = threadIdx.x >> 6;
    int wpb = blockDim.x >> 6;
    int gwave = blockIdx.x * wpb + wib;
    int nwaves = gridDim.x * wpb;

    float w[UNITS];
#pragma unroll
    for (int k = 0; k < UNITS; ++k) w[k] = W[k * UNITS + lane];

    float m = stats[lane] * inv_n;
    float ex2 = stats[UNITS + lane] * inv_n;
    float al = alpha[lane];
    float var = ex2 - m * m * (2.0f * al - al * al);
    float g = gamma[lane] * rsqrtf(var + GN_EPS);
    float A = g;
    float B = beta[lane] - g * al * m;

    for (int nd = gwave; nd < n; nd += nwaves) {
        int node = __builtin_amdgcn_readfirstlane(nd);
        float hv = in[(size_t)node * UNITS + lane];        // coalesced
        float t = fmaf(hv, A, B);
        t = t / (1.0f + __expf(-t));                        // silu, lane-parallel
        lds[wib][lane] = t;                                 // intra-wave dep only
        float di = dinv[node];
        float a0 = 0.0f, a1 = 0.0f, a2 = 0.0f, a3 = 0.0f;
#pragma unroll
        for (int k = 0; k < UNITS; k += 4) {
            float4 tv = *(const float4*)&lds[wib][k];       // uniform-addr broadcast
            a0 = fmaf(tv.x, w[k + 0], a0);
            a1 = fmaf(tv.y, w[k + 1], a1);
            a2 = fmaf(tv.z, w[k + 2], a2);
            a3 = fmaf(tv.w, w[k + 3], a3);
        }
        float acc = (a0 + a1) + (a2 + a3);
        out[(size_t)node * UNITS + lane] = __float2half(acc * di);
    }
}

// ---------------- ParNet linear: out = relu(in + in @ W + b) ----------------

__global__ void k_linear_par(const float* __restrict__ in, float* __restrict__ out,
                             const float* __restrict__ W, const float* __restrict__ b, int n) {
    int lane = threadIdx.x & 63;
    int wib = threadIdx.x >> 6;
    int wpb = blockDim.x >> 6;
    int gwave = blockIdx.x * wpb + wib;
    int nwaves = gridDim.x * wpb;

    float w[UNITS];
#pragma unroll
    for (int k = 0; k < UNITS; ++k) w[k] = W[k * UNITS + lane];
    float bj = b[lane];

    for (int nd = gwave; nd < n; nd += nwaves) {
        int node = __builtin_amdgcn_readfirstlane(nd);
        const float* __restrict__ row = in + (size_t)node * UNITS;
        float a0 = 0.0f, a1 = 0.0f, a2 = 0.0f, a3 = 0.0f;
#pragma unroll
        for (int k = 0; k < UNITS; k += 4) {
            a0 = fmaf(row[k + 0], w[k + 0], a0);
            a1 = fmaf(row[k + 1], w[k + 1], a1);
            a2 = fmaf(row[k + 2], w[k + 2], a2);
            a3 = fmaf(row[k + 3], w[k + 3], a3);
        }
        float acc = (a0 + a1) + (a2 + a3) + row[lane] + bj;
        acc = fmaxf(acc, 0.0f);
        out[(size_t)node * UNITS + lane] = acc;
    }
}

// ---------------- ParNet final linear + head fused ----------------

__global__ void k_linear_head(const float* __restrict__ in, const float* __restrict__ W,
                              const float* __restrict__ b, const float* __restrict__ wl,
                              const float* __restrict__ bl, float* __restrict__ out, int n) {
    int lane = threadIdx.x & 63;
    int wib = threadIdx.x >> 6;
    int wpb = blockDim.x >> 6;
    int gwave = blockIdx.x * wpb + wib;
    int nwaves = gridDim.x * wpb;

    float w[UNITS];
#pragma unroll
    for (int k = 0; k < UNITS; ++k) w[k] = W[k * UNITS + lane];
    float bj = b[lane];
    float wv = wl[lane];
    float blv = bl[0];

    for (int nd = gwave; nd < n; nd += nwaves) {
        int node = __builtin_amdgcn_readfirstlane(nd);
        const float* __restrict__ row = in + (size_t)node * UNITS;
        float a0 = 0.0f, a1 = 0.0f, a2 = 0.0f, a3 = 0.0f;
#pragma unroll
        for (int k = 0; k < UNITS; k += 4) {
            a0 = fmaf(row[k + 0], w[k + 0], a0);
            a1 = fmaf(row[k + 1], w[k + 1], a1);
            a2 = fmaf(row[k + 2], w[k + 2], a2);
            a3 = fmaf(row[k + 3], w[k + 3], a3);
        }
        float acc = (a0 + a1) + (a2 + a3) + row[lane] + bj;
        acc = fmaxf(acc, 0.0f);
        float p = acc * wv;
#pragma unroll
        for (int off = 32; off > 0; off >>= 1) p += __shfl_xor(p, off, 64);
        if (lane == 0) out[node] = 1.0f / (1.0f + __expf(-(p + blv)));
    }
}

// ---------------- host launch ----------------

extern "C" void kernel_launch(void* const* d_in, const int* in_sizes, int n_in,
                              void* d_out, int out_size, void* d_ws, size_t ws_size,
                              hipStream_t stream) {
    const float* x = (const float*)d_in[0];
    const int* ei = (const int*)d_in[1];
    const float* conv_w0 = (const float*)d_in[2];
    const float* conv_w = (const float*)d_in[3];
    const float* conv_b = (const float*)d_in[4];
    const float* gn_gamma = (const float*)d_in[5];
    const float* gn_beta = (const float*)d_in[6];
    const float* gn_alpha = (const float*)d_in[7];
    const float* phe_w = (const float*)d_in[8];
    const float* phe_b = (const float*)d_in[9];
    const float* phe_wl = (const float*)d_in[10];
    const float* phe_bl = (const float*)d_in[11];
    const float* heu_w = (const float*)d_in[12];
    const float* heu_b = (const float*)d_in[13];
    const float* heu_wl = (const float*)d_in[14];
    const float* heu_bl = (const float*)d_in[15];

    const int N = in_sizes[0];
    const int E = in_sizes[1] / 2;
    const int NC = N * UNITS;
    const int NCHUNK1024 = (N + 1023) / 1024;
    const int NB = (N + 255) / 256;
    const int EPB = (E + NFILLB - 1) / NFILLB;

    const int* src = ei;
    const int* dstp = ei + E;

    char* w = (char*)d_ws;
    float* dinv = (float*)w;  w += (size_t)N * 4;
    float* h = (float*)w;     w += (size_t)NC * 4;    // fp32 h (gather out, nsl in, ParNet in)
    float* hx = (float*)w;    w += (size_t)NC * 4;    // f16 h2 (embedding) / parnet scratch
    float* h3 = (float*)w;    w += (size_t)NC * 4;    // pairs (CSR build) / parnet scratch
    float* stats = (float*)w; w += (size_t)DEPTH_EMB * 128 * 4;
    int* cnt = (int*)w;       w += (size_t)N * 4;
    int* rowptr = (int*)w;    w += (size_t)(N + 1) * 4;
    int* fillc = (int*)w;     w += (size_t)N * 4;
    int* srcs = (int*)w;      w += (size_t)(E + 16) * 4;
    int* csum = (int*)w;      w += 256 * 4;
    int* coff = (int*)w;      w += 256 * 4;
    int* table = (int*)w;     w += (size_t)MAXNB * NFILLB * 4;
    int* btot = (int*)w;      w += MAXNB * 4;
    int* boff = (int*)w;      w += MAXNB * 4;

    __half* h2 = (__half*)hx;
    unsigned long long* pairs = (unsigned long long*)h3;  // aliases parnet scratch
    float* out = (float*)d_out;

    const int B = 256;
    const int gE = (E + B - 1) / B;
    const int gN = (N + B - 1) / B;
    const int gNC = (NC + B - 1) / B;

    // ---- CSR build (bucketed fill) ----
    hipMemsetAsync(cnt, 0, (size_t)N * 4, stream);
    hipMemsetAsync(fillc, 0, (size_t)N * 4, stream);
    hipMemsetAsync(stats, 0, (size_t)DEPTH_EMB * 128 * 4, stream);
    k_deg<<<gE, B, 0, stream>>>(dstp, cnt, E);
    k_dinv<<<gN, B, 0, stream>>>(cnt, dinv, N);
    k_chunksum<<<NCHUNK1024, 256, 0, stream>>>(cnt, csum, N);
    k_scansum<<<1, 256, 0, stream>>>(csum, coff, rowptr, NCHUNK1024);
    k_scanfinal<<<NCHUNK1024, 1024, 0, stream>>>(cnt, coff, rowptr, N);
    k_bcount<<<NFILLB, 256, 0, stream>>>(dstp, table, E, NB, EPB);
    k_bscan<<<NB, NFILLB, 0, stream>>>(table, btot);
    k_boffscan<<<1, MAXNB, 0, stream>>>(btot, boff, NB);
    k_bscatter<<<NFILLB, 256, 0, stream>>>(src, dstp, table, boff, pairs, E, NB, EPB);
    k_pfill<<<2048, B, 0, stream>>>(pairs, rowptr, fillc, srcs, E);

    // ---- GCN embedding ----
    k_l0<<<gNC, B, 0, stream>>>(x, conv_w0, dinv, h2, N);
    for (int i = 0; i < DEPTH_EMB; ++i) {
        float* st = stats + (size_t)i * 128;
        if (i < DEPTH_EMB - 1) {
            k_gather<1><<<2048, B, 0, stream>>>(h2, h, rowptr, srcs, dinv,
                                                conv_b + (size_t)i * UNITS, st, N);
            k_nsl<<<2048, B, 0, stream>>>(h, h2, conv_w + (size_t)i * UNITS * UNITS,
                                          dinv, st,
                                          gn_gamma + (size_t)i * UNITS,
                                          gn_beta + (size_t)i * UNITS,
                                          gn_alpha + (size_t)i * UNITS,
                                          1.0f / (float)N, N);
        } else {
            k_gather<0><<<2048, B, 0, stream>>>(h2, h, rowptr, srcs, dinv,
                                                conv_b + (size_t)i * UNITS, st, N);
        }
    }

    // ---- ParNet heads (h preserved; scratch h3/hx) ----
    for (int head = 0; head < 2; ++head) {
        const float* wsrc = head == 0 ? phe_w : heu_w;
        const float* bsrc = head == 0 ? phe_b : heu_b;
        const float* wl = head == 0 ? phe_wl : heu_wl;
        const float* bl = head == 0 ? phe_bl : heu_bl;
        float* o = out + (size_t)head * N;

        k_linear_par<<<2048, B, 0, stream>>>(h, h3, wsrc, bsrc, N);
        k_linear_par<<<2048, B, 0, stream>>>(h3, hx, wsrc + (size_t)1 * UNITS * UNITS,
                                             bsrc + (size_t)1 * UNITS, N);
        k_linear_par<<<2048, B, 0, stream>>>(hx, h3, wsrc + (size_t)2 * UNITS * UNITS,
                                             bsrc + (size_t)2 * UNITS, N);
        k_linear_head<<<2048, B, 0, stream>>>(h3, wsrc + (size_t)3 * UNITS * UNITS,
                                              bsrc + (size_t)3 * UNITS, wl, bl, o, N);
    }
}